// Round 2
// baseline (381.017 us; speedup 1.0000x reference)
//
#include <hip/hip_runtime.h>
#include <math.h>

// SpectralModule: out[b,c,n,e] = sum_f |rfft13(x[b,c,n,:])[f]|/13 * W[f,e] + b[e]
// x [32,64,128,13] f32, W [7,512] f32, b [512] f32, out [32,64,128,512] f32.
// HBM-write-bound (512 MiB out). Phase-split: DFT mags -> LDS -> streaming store.

constexpr int T = 13;
constexpr int F = 7;     // T/2 + 1
constexpr int E = 512;
constexpr int ROWS = 256; // rows per block tile (== blockDim.x)

// cos/sin(2*pi*k/13), k = 0..12 (sign of sin irrelevant for magnitude)
__device__ __constant__ const float CC[T] = {
     1.0f,
     0.8854560256532099f,  0.5680647467311558f,  0.1205366802553230f,
    -0.3546048870425356f, -0.7485107481711011f, -0.9709418174260520f,
    -0.9709418174260520f, -0.7485107481711011f, -0.3546048870425356f,
     0.1205366802553230f,  0.5680647467311558f,  0.8854560256532099f
};
__device__ __constant__ const float SS[T] = {
     0.0f,
     0.4647231720437686f,  0.8229838658936564f,  0.9927088740980540f,
     0.9350162426854148f,  0.6631226582407952f,  0.2393156642875578f,
    -0.2393156642875578f, -0.6631226582407952f, -0.9350162426854148f,
    -0.9927088740980540f, -0.8229838658936564f, -0.4647231720437686f
};

__global__ __launch_bounds__(256, 4) void spectral_kernel(
    const float* __restrict__ x,
    const float* __restrict__ W,
    const float* __restrict__ bias,
    float* __restrict__ out)
{
    __shared__ float sx[ROWS * T];     // 13312 B, x tile
    __shared__ float smag[ROWS][8];    // 8192 B, magnitudes (padded to 8)

    const int tid = threadIdx.x;
    const int lane = tid & 63;
    const int wave = tid >> 6;
    const long long tile_base = (long long)blockIdx.x * ROWS;

    // ---- stage x tile into LDS, coalesced ----
    const float* __restrict__ xg = x + tile_base * T;
#pragma unroll
    for (int k = 0; k < T; ++k) {
        sx[k * ROWS + tid] = xg[k * ROWS + tid];
    }
    __syncthreads();

    // ---- phase 1: thread r computes the 7 rfft bin magnitudes of row r ----
    {
        float xv[T];
#pragma unroll
        for (int t = 0; t < T; ++t) xv[t] = sx[tid * T + t];  // stride-13: conflict-free

        float mg[8];
        // f = 0: pure sum
        {
            float s = xv[0];
#pragma unroll
            for (int t = 1; t < T; ++t) s += xv[t];
            mg[0] = fabsf(s) * (1.0f / 13.0f);
        }
#pragma unroll
        for (int f = 1; f < F; ++f) {
            float re = xv[0];
            float im = 0.0f;
#pragma unroll
            for (int t = 1; t < T; ++t) {
                const int k = (f * t) % T;   // compile-time constant
                re = fmaf(xv[t], CC[k], re);
                im = fmaf(xv[t], SS[k], im);
            }
            mg[f] = sqrtf(fmaf(re, re, im * im)) * (1.0f / 13.0f);
        }
        mg[7] = 0.0f;

        float4 m0 = make_float4(mg[0], mg[1], mg[2], mg[3]);
        float4 m1 = make_float4(mg[4], mg[5], mg[6], mg[7]);
        *reinterpret_cast<float4*>(&smag[tid][0]) = m0;
        *reinterpret_cast<float4*>(&smag[tid][4]) = m1;
    }
    __syncthreads();

    // ---- phase 2: streaming store. Wave w owns rows [w*64, w*64+64).
    // Lane i owns cols [4i,4i+4) and [256+4i, 256+4i+4): each dwordx4 store
    // across the wave covers a contiguous 1 KiB span.
    const int e0 = lane * 4;
    float4 w0[F], w1[F];
#pragma unroll
    for (int f = 0; f < F; ++f) {
        w0[f] = *reinterpret_cast<const float4*>(W + f * E + e0);
        w1[f] = *reinterpret_cast<const float4*>(W + f * E + 256 + e0);
    }
    const float4 b0 = *reinterpret_cast<const float4*>(bias + e0);
    const float4 b1 = *reinterpret_cast<const float4*>(bias + 256 + e0);

    const int r0 = wave * 64;
#pragma unroll 2
    for (int r = r0; r < r0 + 64; ++r) {
        const float4 m0 = *reinterpret_cast<const float4*>(&smag[r][0]);  // broadcast
        const float4 m1 = *reinterpret_cast<const float4*>(&smag[r][4]);
        const float m[F] = {m0.x, m0.y, m0.z, m0.w, m1.x, m1.y, m1.z};

        float4 a0 = b0, a1 = b1;
#pragma unroll
        for (int f = 0; f < F; ++f) {
            a0.x = fmaf(m[f], w0[f].x, a0.x);
            a0.y = fmaf(m[f], w0[f].y, a0.y);
            a0.z = fmaf(m[f], w0[f].z, a0.z);
            a0.w = fmaf(m[f], w0[f].w, a0.w);
            a1.x = fmaf(m[f], w1[f].x, a1.x);
            a1.y = fmaf(m[f], w1[f].y, a1.y);
            a1.z = fmaf(m[f], w1[f].z, a1.z);
            a1.w = fmaf(m[f], w1[f].w, a1.w);
        }

        float* __restrict__ orow = out + (tile_base + r) * (long long)E;
        *reinterpret_cast<float4*>(orow + e0) = a0;
        *reinterpret_cast<float4*>(orow + 256 + e0) = a1;
    }
}

extern "C" void kernel_launch(void* const* d_in, const int* in_sizes, int n_in,
                              void* d_out, int out_size, void* d_ws, size_t ws_size,
                              hipStream_t stream) {
    const float* x = (const float*)d_in[0];
    const float* W = (const float*)d_in[1];
    const float* b = (const float*)d_in[2];
    float* out = (float*)d_out;

    const int nrows = in_sizes[0] / T;          // 262144
    const int blocks = nrows / ROWS;            // 1024 (exact)

    spectral_kernel<<<blocks, 256, 0, stream>>>(x, W, b, out);
}

// Round 3
// 106.007 us; speedup vs baseline: 3.5943x; 3.5943x over previous
//
#include <hip/hip_runtime.h>
#include <math.h>

// SpectralModule: out[b,c,n,e] = sum_f |rfft13(x[b,c,n,:])[f]|/13 * W[f,e] + b[e]
// x [32,64,128,13] f32, W [7,512] f32, b [512] f32, out [32,64,128,512] f32.
// HBM-write-bound (512 MiB out). Hot loop reads ONLY LDS+regs so stores
// (vmcnt) are never drained mid-loop; per-lane W hoist is just 32 VGPRs.

constexpr int T = 13;
constexpr int F = 7;      // T/2 + 1
constexpr int E = 512;
constexpr int ROWS = 128; // rows per block

typedef float f4 __attribute__((ext_vector_type(4)));

__global__ __launch_bounds__(256, 4) void spectral_kernel(
    const float* __restrict__ x,
    const float* __restrict__ Wm,
    const float* __restrict__ bias,
    float* __restrict__ out)
{
    // Twiddles as constexpr so they fold to inline literals (no memory reads).
    constexpr float CC[T] = {
         1.0f,
         0.8854560256532099f,  0.5680647467311558f,  0.1205366802553230f,
        -0.3546048870425356f, -0.7485107481711011f, -0.9709418174260520f,
        -0.9709418174260520f, -0.7485107481711011f, -0.3546048870425356f,
         0.1205366802553230f,  0.5680647467311558f,  0.8854560256532099f
    };
    constexpr float SS[T] = {
         0.0f,
         0.4647231720437686f,  0.8229838658936564f,  0.9927088740980540f,
         0.9350162426854148f,  0.6631226582407952f,  0.2393156642875578f,
        -0.2393156642875578f, -0.6631226582407952f, -0.9350162426854148f,
        -0.9927088740980540f, -0.8229838658936564f, -0.4647231720437686f
    };

    __shared__ float sx[ROWS * T];    // 6656 B, staged x tile
    __shared__ float smag[F][ROWS];   // 3584 B, transposed: contiguous writes,
                                      //          broadcast reads

    const int tid  = threadIdx.x;
    const int lane = tid & 63;
    const int wave = tid >> 6;
    const long long tile_base = (long long)blockIdx.x * ROWS;

    // Per-lane column ownership: wave quadrant = (row half, col half).
    const int c0 = (wave & 1) * 256 + lane * 4;

    // Issue W/bias register loads early; latency overlaps staging + phase 1.
    // Only 7+1 float4 = 32 VGPRs per lane.
    f4 wreg[F];
#pragma unroll
    for (int f = 0; f < F; ++f)
        wreg[f] = *reinterpret_cast<const f4*>(Wm + f * E + c0);
    const f4 breg = *reinterpret_cast<const f4*>(bias + c0);

    // Stage x tile into LDS, coalesced (1664 floats).
    const float* __restrict__ xg = x + tile_base * T;
#pragma unroll
    for (int k = 0; k < 7; ++k) {
        const int idx = k * 256 + tid;
        if (idx < ROWS * T) sx[idx] = xg[idx];
    }
    __syncthreads();

    // Phase 1: two threads per row (wave-uniform split).
    // tid<128 -> bins 0..3 of row tid; tid>=128 -> bins 4..6 of row tid-128.
    {
        const int row = tid & 127;
        float xv[T];
#pragma unroll
        for (int t = 0; t < T; ++t) xv[t] = sx[row * T + t];

        if (tid < 128) {
            float s = xv[0];
#pragma unroll
            for (int t = 1; t < T; ++t) s += xv[t];
            smag[0][row] = fabsf(s) * (1.0f / 13.0f);
#pragma unroll
            for (int f = 1; f < 4; ++f) {
                float re = xv[0], im = 0.0f;
#pragma unroll
                for (int t = 1; t < T; ++t) {
                    const int k = (f * t) % T;   // compile-time
                    re = fmaf(xv[t], CC[k], re);
                    im = fmaf(xv[t], SS[k], im);
                }
                smag[f][row] = sqrtf(fmaf(re, re, im * im)) * (1.0f / 13.0f);
            }
        } else {
#pragma unroll
            for (int f = 4; f < 7; ++f) {
                float re = xv[0], im = 0.0f;
#pragma unroll
                for (int t = 1; t < T; ++t) {
                    const int k = (f * t) % T;   // compile-time
                    re = fmaf(xv[t], CC[k], re);
                    im = fmaf(xv[t], SS[k], im);
                }
                smag[f][row] = sqrtf(fmaf(re, re, im * im)) * (1.0f / 13.0f);
            }
        }
    }
    __syncthreads();

    // Phase 2: streaming store. Wave owns rows [r0, r0+64) x cols [c0 half].
    // Hot loop: 7 broadcast LDS reads (lgkmcnt) + 28 FMA + 1 nt store (vmcnt).
    // Nothing ever waits on the stores.
    const int r0 = (wave >> 1) * 64;
    float* __restrict__ obase = out + (tile_base + r0) * (long long)E + c0;

#pragma unroll 4
    for (int r = 0; r < 64; ++r) {
        f4 a = breg;
#pragma unroll
        for (int f = 0; f < F; ++f) {
            const float m = smag[f][r0 + r];  // wave-uniform -> broadcast
            a.x = fmaf(m, wreg[f].x, a.x);
            a.y = fmaf(m, wreg[f].y, a.y);
            a.z = fmaf(m, wreg[f].z, a.z);
            a.w = fmaf(m, wreg[f].w, a.w);
        }
        __builtin_nontemporal_store(a, reinterpret_cast<f4*>(obase + (long long)r * E));
    }
}

extern "C" void kernel_launch(void* const* d_in, const int* in_sizes, int n_in,
                              void* d_out, int out_size, void* d_ws, size_t ws_size,
                              hipStream_t stream) {
    const float* x = (const float*)d_in[0];
    const float* W = (const float*)d_in[1];
    const float* b = (const float*)d_in[2];
    float* out = (float*)d_out;

    const int nrows = in_sizes[0] / T;      // 262144
    const int blocks = nrows / ROWS;        // 2048 (exact)

    spectral_kernel<<<blocks, 256, 0, stream>>>(x, W, b, out);
}

// Round 4
// 102.784 us; speedup vs baseline: 3.7070x; 1.0314x over previous
//
#include <hip/hip_runtime.h>
#include <math.h>

// SpectralModule: out[b,c,n,e] = sum_f |rfft13(x[b,c,n,:])[f]|/13 * W[f,e] + b[e]
// x [32,64,128,13] f32, W [7,512] f32, b [512] f32, out [32,64,128,512] f32.
// HBM-write-bound (512 MiB out). All 2048 blocks resident (8/CU) -> one global
// staging bubble, then a single uninterrupted store stream at fill-rate.
// VGPR discipline (round-2 lesson): W hoist is 32 VGPR, loaded AFTER phase 1
// so phase lifetimes don't overlap; cap is 64 (launch_bounds 256,8).

constexpr int T = 13;
constexpr int F = 7;      // T/2 + 1
constexpr int E = 512;
constexpr int ROWS = 128; // rows per block

typedef float f4 __attribute__((ext_vector_type(4)));

__global__ __launch_bounds__(256, 8) void spectral_kernel(
    const float* __restrict__ x,
    const float* __restrict__ Wm,
    const float* __restrict__ bias,
    float* __restrict__ out)
{
    // Twiddles fold to inline literals (no memory reads).
    constexpr float CC[T] = {
         1.0f,
         0.8854560256532099f,  0.5680647467311558f,  0.1205366802553230f,
        -0.3546048870425356f, -0.7485107481711011f, -0.9709418174260520f,
        -0.9709418174260520f, -0.7485107481711011f, -0.3546048870425356f,
         0.1205366802553230f,  0.5680647467311558f,  0.8854560256532099f
    };
    constexpr float SS[T] = {
         0.0f,
         0.4647231720437686f,  0.8229838658936564f,  0.9927088740980540f,
         0.9350162426854148f,  0.6631226582407952f,  0.2393156642875578f,
        -0.2393156642875578f, -0.6631226582407952f, -0.9350162426854148f,
        -0.9927088740980540f, -0.8229838658936564f, -0.4647231720437686f
    };

    __shared__ float sx[ROWS * T];    // 6656 B
    __shared__ float smag[F][ROWS];   // 3584 B

    const int tid  = threadIdx.x;
    const int lane = tid & 63;
    const int wave = tid >> 6;
    const long long tile_base = (long long)blockIdx.x * ROWS;

    // ---- stage x tile into LDS, coalesced ----
    const float* __restrict__ xg = x + tile_base * T;
#pragma unroll
    for (int k = 0; k < 7; ++k) {
        const int idx = k * 256 + tid;
        if (idx < ROWS * T) sx[idx] = xg[idx];
    }
    __syncthreads();

    // ---- phase 1: two threads per row; live set ~25 VGPR ----
    {
        const int row = tid & 127;
        float xv[T];
#pragma unroll
        for (int t = 0; t < T; ++t) xv[t] = sx[row * T + t];  // stride-13: free

        if (tid < 128) {
            float s = xv[0];
#pragma unroll
            for (int t = 1; t < T; ++t) s += xv[t];
            smag[0][row] = fabsf(s) * (1.0f / 13.0f);
#pragma unroll
            for (int f = 1; f < 4; ++f) {
                float re = xv[0], im = 0.0f;
#pragma unroll
                for (int t = 1; t < T; ++t) {
                    const int k = (f * t) % T;   // compile-time
                    re = fmaf(xv[t], CC[k], re);
                    im = fmaf(xv[t], SS[k], im);
                }
                smag[f][row] = sqrtf(fmaf(re, re, im * im)) * (1.0f / 13.0f);
            }
        } else {
#pragma unroll
            for (int f = 4; f < 7; ++f) {
                float re = xv[0], im = 0.0f;
#pragma unroll
                for (int t = 1; t < T; ++t) {
                    const int k = (f * t) % T;   // compile-time
                    re = fmaf(xv[t], CC[k], re);
                    im = fmaf(xv[t], SS[k], im);
                }
                smag[f][row] = sqrtf(fmaf(re, re, im * im)) * (1.0f / 13.0f);
            }
        }
    }
    __syncthreads();

    // ---- phase 2: W/bias hoist AFTER phase 1 (32 VGPR), then stream ----
    const int c0 = (wave & 1) * 256 + lane * 4;
    f4 wreg[F];
#pragma unroll
    for (int f = 0; f < F; ++f)
        wreg[f] = *reinterpret_cast<const f4*>(Wm + f * E + c0);
    const f4 breg = *reinterpret_cast<const f4*>(bias + c0);

    const int r0 = (wave >> 1) * 64;
    float* __restrict__ obase = out + (tile_base + r0) * (long long)E + c0;

    // Hot loop: 7 broadcast LDS reads + 28 FMA + 1 nt dwordx4 store.
    // Never waits on vmcnt.
#pragma unroll 2
    for (int r = 0; r < 64; ++r) {
        f4 a = breg;
#pragma unroll
        for (int f = 0; f < F; ++f) {
            const float m = smag[f][r0 + r];  // wave-uniform -> broadcast
            a.x = fmaf(m, wreg[f].x, a.x);
            a.y = fmaf(m, wreg[f].y, a.y);
            a.z = fmaf(m, wreg[f].z, a.z);
            a.w = fmaf(m, wreg[f].w, a.w);
        }
        __builtin_nontemporal_store(a, reinterpret_cast<f4*>(obase + (long long)r * E));
    }
}

extern "C" void kernel_launch(void* const* d_in, const int* in_sizes, int n_in,
                              void* d_out, int out_size, void* d_ws, size_t ws_size,
                              hipStream_t stream) {
    const float* x = (const float*)d_in[0];
    const float* W = (const float*)d_in[1];
    const float* b = (const float*)d_in[2];
    float* out = (float*)d_out;

    const int nrows = in_sizes[0] / T;      // 262144
    const int blocks = nrows / ROWS;        // 2048 = 8 per CU, all resident

    spectral_kernel<<<blocks, 256, 0, stream>>>(x, W, b, out);
}